// Round 1
// baseline (201.113 us; speedup 1.0000x reference)
//
#include <hip/hip_runtime.h>

#define BB 4
#define SS 4096
#define DDIM 1024
#define KDIM 64
#define CHUNK 64
#define NCHUNK 64          // SS / CHUNK
#define TCHUNK 256         // BB * NCHUNK
#define MROWS 16384        // BB * SS

__device__ __forceinline__ void ld4(float* d, const float* p) {
    float4 v = *(const float4*)p;
    d[0] = v.x; d[1] = v.y; d[2] = v.z; d[3] = v.w;
}

// XOR swizzle for a [64][64] f32 LDS tile read with row-stride-4 lane patterns.
// slot' = k4 ^ ((r>>2)&7) spreads 16 lanes (rows tx*4+j) across 8 bank groups.
__device__ __forceinline__ int swz(int r, int c) {
    return r * 64 + ((((c >> 2) ^ ((r >> 2) & 7)) << 2) | (c & 3));
}

// ---------------- Kernel 1: fused QKV projection ----------------
// cols 0..63 -> Q (elu+1), 64..127 -> Kf (elu+1), 128..191 -> V
// grid = (MROWS/64)*2, block = 256
__global__ __launch_bounds__(256) void k_proj(
    const float* __restrict__ x, const float* __restrict__ Wq,
    const float* __restrict__ Wk, const float* __restrict__ Wv,
    float* __restrict__ Q, float* __restrict__ Kf, float* __restrict__ V)
{
    __shared__ float xs[64][36];
    __shared__ float wsh[96][36];
    const int t = threadIdx.x;
    const int mt = blockIdx.x >> 1;
    const int nt = blockIdx.x & 1;
    const int tx = t & 15, ty = t >> 4;
    const int row0 = mt * 64;
    const int c0 = nt * 96;

    float acc[4][6];
#pragma unroll
    for (int i = 0; i < 4; ++i)
#pragma unroll
        for (int j = 0; j < 6; ++j) acc[i][j] = 0.f;

    for (int k0 = 0; k0 < DDIM; k0 += 32) {
        // load x tile 64x32 (2 float4 per thread, coalesced)
        {
            const int f = t * 8;
            const int r = f >> 5, kk = f & 31;
            const float* src = &x[(size_t)(row0 + r) * DDIM + k0 + kk];
            float4 a = *(const float4*)(src);
            float4 b = *(const float4*)(src + 4);
            *(float4*)&xs[r][kk] = a;
            *(float4*)&xs[r][kk + 4] = b;
        }
        // load W tile 96x32 (3 float4 per thread)
#pragma unroll
        for (int i = 0; i < 3; ++i) {
            const int f4 = t + i * 256;
            const int r = f4 >> 3;
            const int kk = (f4 & 7) << 2;
            const int c = c0 + r;
            const float* wrow = (c < 64) ? (Wq + (size_t)c * DDIM)
                              : (c < 128) ? (Wk + (size_t)(c - 64) * DDIM)
                                          : (Wv + (size_t)(c - 128) * DDIM);
            *(float4*)&wsh[r][kk] = *(const float4*)&wrow[k0 + kk];
        }
        __syncthreads();
#pragma unroll
        for (int kk = 0; kk < 32; kk += 4) {
            float xv[4][4], wv[6][4];
#pragma unroll
            for (int i = 0; i < 4; ++i) ld4(xv[i], &xs[ty * 4 + i][kk]);
#pragma unroll
            for (int j = 0; j < 6; ++j) ld4(wv[j], &wsh[tx * 6 + j][kk]);
#pragma unroll
            for (int i = 0; i < 4; ++i)
#pragma unroll
                for (int j = 0; j < 6; ++j)
#pragma unroll
                    for (int q = 0; q < 4; ++q)
                        acc[i][j] = fmaf(xv[i][q], wv[j][q], acc[i][j]);
        }
        __syncthreads();
    }
#pragma unroll
    for (int i = 0; i < 4; ++i) {
        const int row = row0 + ty * 4 + i;
#pragma unroll
        for (int j = 0; j < 6; ++j) {
            const int c = c0 + tx * 6 + j;
            float v = acc[i][j];
            if (c < 128) v = (v > 0.f) ? v + 1.f : __expf(v);  // elu(v)+1
            if (c < 64)       Q[(size_t)row * KDIM + c] = v;
            else if (c < 128) Kf[(size_t)row * KDIM + (c - 64)] = v;
            else              V[(size_t)row * KDIM + (c - 128)] = v;
        }
    }
}

// ---------------- Kernel 2: per-chunk KV summary ----------------
// KVc[g][k][m] = sum_j Kf[g*64+j][k] * V[g*64+j][m] ; Ksc[g][k] = sum_j Kf[..][k]
// grid = TCHUNK, block = 256
__global__ __launch_bounds__(256) void k_chunksum(
    const float* __restrict__ Kf, const float* __restrict__ V,
    float* __restrict__ KVc, float* __restrict__ Ksc)
{
    __shared__ float ks[64][68];
    __shared__ float vs[64][68];
    const int g = blockIdx.x;
    const int t = threadIdx.x;
#pragma unroll
    for (int i = 0; i < 4; ++i) {
        const int f4 = i * 256 + t;
        const int r = f4 >> 4;
        const int kq = (f4 & 15) << 2;
        const size_t gi = ((size_t)g * 64 + r) * KDIM + kq;
        *(float4*)&ks[r][kq] = *(const float4*)&Kf[gi];
        *(float4*)&vs[r][kq] = *(const float4*)&V[gi];
    }
    __syncthreads();
    const int tx = t & 15, ty = t >> 4;
    float acc[4][4];
#pragma unroll
    for (int i = 0; i < 4; ++i)
#pragma unroll
        for (int m = 0; m < 4; ++m) acc[i][m] = 0.f;
    for (int j = 0; j < 64; ++j) {
        float ka[4], va[4];
        ld4(ka, &ks[j][ty * 4]);
        ld4(va, &vs[j][tx * 4]);
#pragma unroll
        for (int i = 0; i < 4; ++i)
#pragma unroll
            for (int m = 0; m < 4; ++m)
                acc[i][m] = fmaf(ka[i], va[m], acc[i][m]);
    }
#pragma unroll
    for (int i = 0; i < 4; ++i)
#pragma unroll
        for (int m = 0; m < 4; ++m)
            KVc[(size_t)g * 4096 + (size_t)(ty * 4 + i) * 64 + tx * 4 + m] = acc[i][m];
    if (t < 64) {
        float s = 0.f;
        for (int j = 0; j < 64; ++j) s += ks[j][t];
        Ksc[(size_t)g * KDIM + t] = s;
    }
}

// ---------------- Kernel 3: exclusive prefix over chunks ----------------
// grid = BB*65 blocks of 64 threads: 64 blocks/batch for the 4096-elem KV
// state, 1 block/batch for the 64-elem Ksum state.
__global__ void k_scan(const float* __restrict__ KVc, const float* __restrict__ Ksc,
                       float* __restrict__ Sst, float* __restrict__ Kss)
{
    const int b = blockIdx.x / 65;
    const int r = blockIdx.x % 65;
    const int t = threadIdx.x;
    float acc = 0.f;
    if (r < 64) {
        const int e = r * 64 + t;
        for (int c = 0; c < NCHUNK; ++c) {
            const size_t idx = ((size_t)(b * NCHUNK + c)) * 4096 + e;
            Sst[idx] = acc;
            acc += KVc[idx];
        }
    } else {
        for (int c = 0; c < NCHUNK; ++c) {
            const size_t idx = ((size_t)(b * NCHUNK + c)) * KDIM + t;
            Kss[idx] = acc;
            acc += Ksc[idx];
        }
    }
}

// ---------------- Kernel 4: intra-chunk attention + state apply ----------------
// grid = TCHUNK, block = 256
__global__ __launch_bounds__(256) void k_intra(
    const float* __restrict__ Q, const float* __restrict__ Kf,
    const float* __restrict__ V, const float* __restrict__ Sst,
    const float* __restrict__ Kss, float* __restrict__ O)
{
    __shared__ float qs[64][68];
    __shared__ float kT[64 * 64];   // swizzled Kf tile
    __shared__ float vs[64][68];
    __shared__ float ss[64][68];
    __shared__ float am[64][68];
    __shared__ float denl[64];
    __shared__ float ksuml[64];
    const int g = blockIdx.x;
    const int t = threadIdx.x;
    const int tx = t & 15, ty = t >> 4;
#pragma unroll
    for (int i = 0; i < 4; ++i) {
        const int f4 = i * 256 + t;
        const int r = f4 >> 4;
        const int kq = (f4 & 15) << 2;
        const size_t gi = ((size_t)g * 64 + r) * KDIM + kq;
        *(float4*)&qs[r][kq] = *(const float4*)&Q[gi];
        *(float4*)&kT[swz(r, kq)] = *(const float4*)&Kf[gi];
        *(float4*)&vs[r][kq] = *(const float4*)&V[gi];
        *(float4*)&ss[r][kq] = *(const float4*)&Sst[(size_t)g * 4096 + (size_t)f4 * 4];
    }
    if (t < 64) ksuml[t] = Kss[(size_t)g * KDIM + t];
    __syncthreads();

    // Phase 1: A[i][j] = dot(Q[i], Kf[j]); rows i = ty*4+., cols j = tx*4+.
    float a[4][4];
#pragma unroll
    for (int i = 0; i < 4; ++i)
#pragma unroll
        for (int j = 0; j < 4; ++j) a[i][j] = 0.f;
    for (int k = 0; k < 64; k += 4) {
        float qv[4][4], kv[4][4];
#pragma unroll
        for (int i = 0; i < 4; ++i) ld4(qv[i], &qs[ty * 4 + i][k]);
#pragma unroll
        for (int j = 0; j < 4; ++j) ld4(kv[j], &kT[swz(tx * 4 + j, k)]);
#pragma unroll
        for (int i = 0; i < 4; ++i)
#pragma unroll
            for (int j = 0; j < 4; ++j)
#pragma unroll
                for (int q = 0; q < 4; ++q)
                    a[i][j] = fmaf(qv[i][q], kv[j][q], a[i][j]);
    }
    // den partials: masked rowsum (this thread's 4 cols) + Q·Ksum (k-range tx*4..+3)
    float dpart[4];
#pragma unroll
    for (int i = 0; i < 4; ++i) {
        const int ri = ty * 4 + i;
        float s = 0.f;
#pragma unroll
        for (int j = 0; j < 4; ++j) {
            const int cj = tx * 4 + j;
            s += (cj <= ri) ? a[i][j] : 0.f;
        }
#pragma unroll
        for (int q = 0; q < 4; ++q)
            s += qs[ri][tx * 4 + q] * ksuml[tx * 4 + q];
        dpart[i] = s;
    }
#pragma unroll
    for (int m = 8; m >= 1; m >>= 1)
#pragma unroll
        for (int i = 0; i < 4; ++i)
            dpart[i] += __shfl_xor(dpart[i], m, 64);
    if (tx == 0) {
#pragma unroll
        for (int i = 0; i < 4; ++i) denl[ty * 4 + i] = dpart[i] + 1e-6f;
    }
    // store causal-masked A
#pragma unroll
    for (int i = 0; i < 4; ++i)
#pragma unroll
        for (int j = 0; j < 4; ++j)
            am[ty * 4 + i][tx * 4 + j] = ((tx * 4 + j) <= (ty * 4 + i)) ? a[i][j] : 0.f;
    __syncthreads();

    // Phase 2: num = A @ V + Q @ Sst ; O = num / den
    float acc[4][4];
#pragma unroll
    for (int i = 0; i < 4; ++i)
#pragma unroll
        for (int m = 0; m < 4; ++m) acc[i][m] = 0.f;
    for (int j = 0; j < 64; j += 4) {
        float av[4][4], vv[4][4];
#pragma unroll
        for (int i = 0; i < 4; ++i) ld4(av[i], &am[ty * 4 + i][j]);
#pragma unroll
        for (int jj = 0; jj < 4; ++jj) ld4(vv[jj], &vs[j + jj][tx * 4]);
#pragma unroll
        for (int jj = 0; jj < 4; ++jj)
#pragma unroll
            for (int i = 0; i < 4; ++i)
#pragma unroll
                for (int m = 0; m < 4; ++m)
                    acc[i][m] = fmaf(av[i][jj], vv[jj][m], acc[i][m]);
    }
    for (int k = 0; k < 64; k += 4) {
        float qv[4][4], sv[4][4];
#pragma unroll
        for (int i = 0; i < 4; ++i) ld4(qv[i], &qs[ty * 4 + i][k]);
#pragma unroll
        for (int kk = 0; kk < 4; ++kk) ld4(sv[kk], &ss[k + kk][tx * 4]);
#pragma unroll
        for (int kk = 0; kk < 4; ++kk)
#pragma unroll
            for (int i = 0; i < 4; ++i)
#pragma unroll
                for (int m = 0; m < 4; ++m)
                    acc[i][m] = fmaf(qv[i][kk], sv[kk][m], acc[i][m]);
    }
#pragma unroll
    for (int i = 0; i < 4; ++i) {
        const float dinv = 1.f / denl[ty * 4 + i];
#pragma unroll
        for (int m = 0; m < 4; ++m)
            O[((size_t)g * 64 + ty * 4 + i) * KDIM + tx * 4 + m] = acc[i][m] * dinv;
    }
}

// ---------------- Kernel 5: output projection ----------------
// out[m][d] = dot(O[m][:], Wo[d][:]) ; grid = 256*8, block = 256
__global__ __launch_bounds__(256) void k_outproj(
    const float* __restrict__ O, const float* __restrict__ Wo,
    float* __restrict__ out)
{
    __shared__ float os[64][68];
    __shared__ float wos[128][68];
    const int t = threadIdx.x;
    const int mt = blockIdx.x >> 3;
    const int nt = blockIdx.x & 7;
    const int tx = t & 15, ty = t >> 4;
    const int row0 = mt * 64, c0 = nt * 128;
#pragma unroll
    for (int i = 0; i < 4; ++i) {
        const int f4 = i * 256 + t;
        const int r = f4 >> 4, kq = (f4 & 15) << 2;
        *(float4*)&os[r][kq] = *(const float4*)&O[((size_t)row0 + r) * KDIM + kq];
    }
#pragma unroll
    for (int i = 0; i < 8; ++i) {
        const int f4 = i * 256 + t;
        const int r = f4 >> 4, kq = (f4 & 15) << 2;
        *(float4*)&wos[r][kq] = *(const float4*)&Wo[((size_t)(c0 + r)) * KDIM + kq];
    }
    __syncthreads();
    float acc[4][8];
#pragma unroll
    for (int i = 0; i < 4; ++i)
#pragma unroll
        for (int j = 0; j < 8; ++j) acc[i][j] = 0.f;
    for (int k = 0; k < 64; k += 4) {
        float ov[4][4], wv[8][4];
#pragma unroll
        for (int i = 0; i < 4; ++i) ld4(ov[i], &os[ty * 4 + i][k]);
#pragma unroll
        for (int j = 0; j < 8; ++j) ld4(wv[j], &wos[tx + j * 16][k]);
#pragma unroll
        for (int i = 0; i < 4; ++i)
#pragma unroll
            for (int j = 0; j < 8; ++j)
#pragma unroll
                for (int q = 0; q < 4; ++q)
                    acc[i][j] = fmaf(ov[i][q], wv[j][q], acc[i][j]);
    }
#pragma unroll
    for (int i = 0; i < 4; ++i) {
        const size_t ro = ((size_t)row0 + ty * 4 + i) * DDIM + c0;
#pragma unroll
        for (int j = 0; j < 8; ++j) out[ro + tx + j * 16] = acc[i][j];
    }
}

extern "C" void kernel_launch(void* const* d_in, const int* in_sizes, int n_in,
                              void* d_out, int out_size, void* d_ws, size_t ws_size,
                              hipStream_t stream)
{
    const float* x  = (const float*)d_in[0];
    const float* Wq = (const float*)d_in[1];
    const float* Wk = (const float*)d_in[2];
    const float* Wv = (const float*)d_in[3];
    const float* Wo = (const float*)d_in[4];
    float* out = (float*)d_out;

    // workspace layout (floats); total 6,324,224 floats = 25.3 MB
    float* ws  = (float*)d_ws;
    float* Q   = ws;
    float* Kf  = Q  + (size_t)MROWS * KDIM;
    float* V   = Kf + (size_t)MROWS * KDIM;
    float* O   = V  + (size_t)MROWS * KDIM;
    float* KVc = O  + (size_t)MROWS * KDIM;
    float* Sst = KVc + (size_t)TCHUNK * KDIM * KDIM;
    float* Ksc = Sst + (size_t)TCHUNK * KDIM * KDIM;
    float* Kss = Ksc + (size_t)TCHUNK * KDIM;

    k_proj<<<dim3((MROWS / 64) * 2), dim3(256), 0, stream>>>(x, Wq, Wk, Wv, Q, Kf, V);
    k_chunksum<<<dim3(TCHUNK), dim3(256), 0, stream>>>(Kf, V, KVc, Ksc);
    k_scan<<<dim3(BB * 65), dim3(64), 0, stream>>>(KVc, Ksc, Sst, Kss);
    k_intra<<<dim3(TCHUNK), dim3(256), 0, stream>>>(Q, Kf, V, Sst, Kss, O);
    k_outproj<<<dim3((MROWS / 64) * (DDIM / 128)), dim3(256), 0, stream>>>(O, Wo, out);
}

// Round 2
// 89.187 us; speedup vs baseline: 2.2550x; 2.2550x over previous
//
#include <hip/hip_runtime.h>

#define BB 4
#define SS 4096
#define DDIM 1024
#define KDIM 64
#define CHUNK 64
#define NCHUNK 64          // SS / CHUNK
#define TCHUNK 256         // BB * NCHUNK
#define MROWS 16384        // BB * SS

typedef short short8v __attribute__((ext_vector_type(8)));
typedef float f32x4 __attribute__((ext_vector_type(4)));
#define MFMA16 __builtin_amdgcn_mfma_f32_16x16x32_bf16

__device__ __forceinline__ ushort f2bf(float f) {
    // round-to-nearest-even f32 -> bf16
    uint u = __float_as_uint(f);
    u += 0x7FFFu + ((u >> 16) & 1u);
    return (ushort)(u >> 16);
}

__device__ __forceinline__ void ld4(float* d, const float* p) {
    float4 v = *(const float4*)p;
    d[0] = v.x; d[1] = v.y; d[2] = v.z; d[3] = v.w;
}

// XOR swizzle used by k_intra's Kf tile (kept from R1)
__device__ __forceinline__ int swz(int r, int c) {
    return r * 64 + ((((c >> 2) ^ ((r >> 2) & 7)) << 2) | (c & 3));
}

// ---------------- Kernel 0: weight conversion f32 -> bf16 ----------------
// blocks 0..191: Wqkv row b (1024 elems) -> Wh[b][.]
// blocks 192..447: Wo flat chunk of 256 elems -> Woh
__global__ __launch_bounds__(256) void k_wconv(
    const float* __restrict__ Wq, const float* __restrict__ Wk,
    const float* __restrict__ Wv, const float* __restrict__ Wo,
    ushort* __restrict__ Wh, ushort* __restrict__ Woh)
{
    const int b = blockIdx.x, t = threadIdx.x;
    if (b < 192) {
        const float* src = (b < 64) ? (Wq + (size_t)b * DDIM)
                         : (b < 128) ? (Wk + (size_t)(b - 64) * DDIM)
                                     : (Wv + (size_t)(b - 128) * DDIM);
#pragma unroll
        for (int i = 0; i < 4; ++i)
            Wh[(size_t)b * DDIM + i * 256 + t] = f2bf(src[i * 256 + t]);
    } else {
        const int off = (b - 192) * 256 + t;   // 256 blocks * 256 = 65536
        Woh[off] = f2bf(Wo[off]);
    }
}

// ---------------- Kernel 1: fused QKV projection (bf16 MFMA) ----------------
// C[16384,192] = x @ [Wq;Wk;Wv]^T ; cols 0..127 get elu()+1.
// BM=64, BN=192, BK=64; grid=256 blocks, 4 waves, wave tile 64x48.
// LDS fragment-linear: frag = 1KB, lane l owns bytes [l*16, l*16+16).
__global__ __launch_bounds__(256) void k_proj(
    const float* __restrict__ x, const ushort* __restrict__ Wh,
    float* __restrict__ Q, float* __restrict__ Kf, float* __restrict__ V)
{
    __shared__ ushort xs[8 * 512];     // 8 frags (4 rf x 2 ks), 8 KB
    __shared__ ushort ws2[24 * 512];   // 24 frags (12 cf x 2 ks), 24 KB
    const int t = threadIdx.x;
    const int w = t >> 6;
    const int l = t & 63;
    const int row0 = blockIdx.x * 64;

    float4 xr[4];  // prefetch regs: 2 slots x 8 f32

    // x slot s (0..511): rf=s>>7, ks=(s>>6)&1, row=rf*16+(s&15), kk=ks*32+((s>>4)&3)*8
    auto ldx = [&](int k0) {
#pragma unroll
        for (int si = 0; si < 2; ++si) {
            const int s = t + si * 256;
            const int row = ((s >> 7) << 4) + (s & 15);
            const int kk = ((s >> 6) & 1) * 32 + ((s >> 4) & 3) * 8;
            const float* p = &x[(size_t)(row0 + row) * DDIM + k0 + kk];
            xr[si * 2 + 0] = *(const float4*)p;
            xr[si * 2 + 1] = *(const float4*)(p + 4);
        }
    };
    auto stx = [&]() {
#pragma unroll
        for (int si = 0; si < 2; ++si) {
            const int s = t + si * 256;
            float ff[8];
            ff[0] = xr[si*2].x; ff[1] = xr[si*2].y; ff[2] = xr[si*2].z; ff[3] = xr[si*2].w;
            ff[4] = xr[si*2+1].x; ff[5] = xr[si*2+1].y; ff[6] = xr[si*2+1].z; ff[7] = xr[si*2+1].w;
            short8v h;
#pragma unroll
            for (int e = 0; e < 8; ++e) h[e] = (short)f2bf(ff[e]);
            *(short8v*)&xs[s * 8] = h;
        }
    };
    // W slot s (0..1535): cf=(s>>6)>>1, ks=(s>>6)&1, n=cf*16+(s&15), kk=ks*32+((s>>4)&3)*8
    auto stw = [&](int k0) {
        short8v wtmp[6];
#pragma unroll
        for (int i = 0; i < 6; ++i) {
            const int s = t + i * 256;
            const int f = s >> 6;
            const int n = (f >> 1) * 16 + (s & 15);
            const int kk = k0 + (f & 1) * 32 + ((s >> 4) & 3) * 8;
            wtmp[i] = *(const short8v*)&Wh[(size_t)n * DDIM + kk];
        }
#pragma unroll
        for (int i = 0; i < 6; ++i) *(short8v*)&ws2[(t + i * 256) * 8] = wtmp[i];
    };

    f32x4 acc[4][3];
#pragma unroll
    for (int r = 0; r < 4; ++r)
#pragma unroll
        for (int c = 0; c < 3; ++c) acc[r][c] = (f32x4){0.f, 0.f, 0.f, 0.f};

    ldx(0);
    for (int step = 0; step < 16; ++step) {
        __syncthreads();                 // LDS free (prev compute done)
        stx();
        stw(step * 64);
        if (step < 15) ldx((step + 1) * 64);
        __syncthreads();                 // LDS ready
#pragma unroll
        for (int ks = 0; ks < 2; ++ks) {
            short8v a[4], b[3];
#pragma unroll
            for (int r = 0; r < 4; ++r)
                a[r] = *(const short8v*)&xs[((r * 2 + ks) * 64 + l) * 8];
#pragma unroll
            for (int c = 0; c < 3; ++c) {
                const int cf = w * 3 + c;
                b[c] = *(const short8v*)&ws2[((cf * 2 + ks) * 64 + l) * 8];
            }
#pragma unroll
            for (int c = 0; c < 3; ++c)
#pragma unroll
                for (int r = 0; r < 4; ++r)
                    acc[r][c] = MFMA16(a[r], b[c], acc[r][c], 0, 0, 0);
        }
    }

    // epilogue: C/D layout col=l&15, row=(l>>4)*4+q
#pragma unroll
    for (int r = 0; r < 4; ++r) {
#pragma unroll
        for (int c = 0; c < 3; ++c) {
            const int col = w * 48 + c * 16 + (l & 15);
#pragma unroll
            for (int q = 0; q < 4; ++q) {
                const int row = row0 + r * 16 + ((l >> 4) << 2) + q;
                float v = acc[r][c][q];
                if (col < 128) v = (v > 0.f) ? v + 1.f : __expf(v);  // elu+1
                if (col < 64)       Q[(size_t)row * KDIM + col] = v;
                else if (col < 128) Kf[(size_t)row * KDIM + (col - 64)] = v;
                else                V[(size_t)row * KDIM + (col - 128)] = v;
            }
        }
    }
}

// ---------------- Kernel 2: per-chunk KV summary ----------------
__global__ __launch_bounds__(256) void k_chunksum(
    const float* __restrict__ Kf, const float* __restrict__ V,
    float* __restrict__ KVc, float* __restrict__ Ksc)
{
    __shared__ float ks[64][68];
    __shared__ float vs[64][68];
    const int g = blockIdx.x;
    const int t = threadIdx.x;
#pragma unroll
    for (int i = 0; i < 4; ++i) {
        const int f4 = i * 256 + t;
        const int r = f4 >> 4;
        const int kq = (f4 & 15) << 2;
        const size_t gi = ((size_t)g * 64 + r) * KDIM + kq;
        *(float4*)&ks[r][kq] = *(const float4*)&Kf[gi];
        *(float4*)&vs[r][kq] = *(const float4*)&V[gi];
    }
    __syncthreads();
    const int tx = t & 15, ty = t >> 4;
    float acc[4][4];
#pragma unroll
    for (int i = 0; i < 4; ++i)
#pragma unroll
        for (int m = 0; m < 4; ++m) acc[i][m] = 0.f;
    for (int j = 0; j < 64; ++j) {
        float ka[4], va[4];
        ld4(ka, &ks[j][ty * 4]);
        ld4(va, &vs[j][tx * 4]);
#pragma unroll
        for (int i = 0; i < 4; ++i)
#pragma unroll
            for (int m = 0; m < 4; ++m)
                acc[i][m] = fmaf(ka[i], va[m], acc[i][m]);
    }
#pragma unroll
    for (int i = 0; i < 4; ++i)
#pragma unroll
        for (int m = 0; m < 4; ++m)
            KVc[(size_t)g * 4096 + (size_t)(ty * 4 + i) * 64 + tx * 4 + m] = acc[i][m];
    if (t < 64) {
        float s = 0.f;
        for (int j = 0; j < 64; ++j) s += ks[j][t];
        Ksc[(size_t)g * KDIM + t] = s;
    }
}

// ---------------- Kernel 3: exclusive prefix over chunks (batched loads) ----------------
__global__ void k_scan(const float* __restrict__ KVc, const float* __restrict__ Ksc,
                       float* __restrict__ Sst, float* __restrict__ Kss)
{
    const int b = blockIdx.x / 65;
    const int r = blockIdx.x % 65;
    const int t = threadIdx.x;
    float acc = 0.f;
    if (r < 64) {
        const int e = r * 64 + t;
        for (int c0 = 0; c0 < NCHUNK; c0 += 8) {
            float v[8];
#pragma unroll
            for (int i = 0; i < 8; ++i)
                v[i] = KVc[((size_t)(b * NCHUNK + c0 + i)) * 4096 + e];
#pragma unroll
            for (int i = 0; i < 8; ++i) {
                Sst[((size_t)(b * NCHUNK + c0 + i)) * 4096 + e] = acc;
                acc += v[i];
            }
        }
    } else {
        for (int c0 = 0; c0 < NCHUNK; c0 += 8) {
            float v[8];
#pragma unroll
            for (int i = 0; i < 8; ++i)
                v[i] = Ksc[((size_t)(b * NCHUNK + c0 + i)) * KDIM + t];
#pragma unroll
            for (int i = 0; i < 8; ++i) {
                Kss[((size_t)(b * NCHUNK + c0 + i)) * KDIM + t] = acc;
                acc += v[i];
            }
        }
    }
}

// ---------------- Kernel 4: intra-chunk attention + state apply ----------------
// Output O now written as bf16 for the MFMA out-projection.
__global__ __launch_bounds__(256) void k_intra(
    const float* __restrict__ Q, const float* __restrict__ Kf,
    const float* __restrict__ V, const float* __restrict__ Sst,
    const float* __restrict__ Kss, ushort* __restrict__ Ob)
{
    __shared__ float qs[64][68];
    __shared__ float kT[64 * 64];
    __shared__ float vs[64][68];
    __shared__ float ss[64][68];
    __shared__ float am[64][68];
    __shared__ float denl[64];
    __shared__ float ksuml[64];
    const int g = blockIdx.x;
    const int t = threadIdx.x;
    const int tx = t & 15, ty = t >> 4;
#pragma unroll
    for (int i = 0; i < 4; ++i) {
        const int f4 = i * 256 + t;
        const int r = f4 >> 4;
        const int kq = (f4 & 15) << 2;
        const size_t gi = ((size_t)g * 64 + r) * KDIM + kq;
        *(float4*)&qs[r][kq] = *(const float4*)&Q[gi];
        *(float4*)&kT[swz(r, kq)] = *(const float4*)&Kf[gi];
        *(float4*)&vs[r][kq] = *(const float4*)&V[gi];
        *(float4*)&ss[r][kq] = *(const float4*)&Sst[(size_t)g * 4096 + (size_t)f4 * 4];
    }
    if (t < 64) ksuml[t] = Kss[(size_t)g * KDIM + t];
    __syncthreads();

    float a[4][4];
#pragma unroll
    for (int i = 0; i < 4; ++i)
#pragma unroll
        for (int j = 0; j < 4; ++j) a[i][j] = 0.f;
    for (int k = 0; k < 64; k += 4) {
        float qv[4][4], kv[4][4];
#pragma unroll
        for (int i = 0; i < 4; ++i) ld4(qv[i], &qs[ty * 4 + i][k]);
#pragma unroll
        for (int j = 0; j < 4; ++j) ld4(kv[j], &kT[swz(tx * 4 + j, k)]);
#pragma unroll
        for (int i = 0; i < 4; ++i)
#pragma unroll
            for (int j = 0; j < 4; ++j)
#pragma unroll
                for (int q = 0; q < 4; ++q)
                    a[i][j] = fmaf(qv[i][q], kv[j][q], a[i][j]);
    }
    float dpart[4];
#pragma unroll
    for (int i = 0; i < 4; ++i) {
        const int ri = ty * 4 + i;
        float s = 0.f;
#pragma unroll
        for (int j = 0; j < 4; ++j) {
            const int cj = tx * 4 + j;
            s += (cj <= ri) ? a[i][j] : 0.f;
        }
#pragma unroll
        for (int q = 0; q < 4; ++q)
            s += qs[ri][tx * 4 + q] * ksuml[tx * 4 + q];
        dpart[i] = s;
    }
#pragma unroll
    for (int m = 8; m >= 1; m >>= 1)
#pragma unroll
        for (int i = 0; i < 4; ++i)
            dpart[i] += __shfl_xor(dpart[i], m, 64);
    if (tx == 0) {
#pragma unroll
        for (int i = 0; i < 4; ++i) denl[ty * 4 + i] = dpart[i] + 1e-6f;
    }
#pragma unroll
    for (int i = 0; i < 4; ++i)
#pragma unroll
        for (int j = 0; j < 4; ++j)
            am[ty * 4 + i][tx * 4 + j] = ((tx * 4 + j) <= (ty * 4 + i)) ? a[i][j] : 0.f;
    __syncthreads();

    float acc[4][4];
#pragma unroll
    for (int i = 0; i < 4; ++i)
#pragma unroll
        for (int m = 0; m < 4; ++m) acc[i][m] = 0.f;
    for (int j = 0; j < 64; j += 4) {
        float av[4][4], vv[4][4];
#pragma unroll
        for (int i = 0; i < 4; ++i) ld4(av[i], &am[ty * 4 + i][j]);
#pragma unroll
        for (int jj = 0; jj < 4; ++jj) ld4(vv[jj], &vs[j + jj][tx * 4]);
#pragma unroll
        for (int jj = 0; jj < 4; ++jj)
#pragma unroll
            for (int i = 0; i < 4; ++i)
#pragma unroll
                for (int m = 0; m < 4; ++m)
                    acc[i][m] = fmaf(av[i][jj], vv[jj][m], acc[i][m]);
    }
    for (int k = 0; k < 64; k += 4) {
        float qv[4][4], sv[4][4];
#pragma unroll
        for (int i = 0; i < 4; ++i) ld4(qv[i], &qs[ty * 4 + i][k]);
#pragma unroll
        for (int kk = 0; kk < 4; ++kk) ld4(sv[kk], &ss[k + kk][tx * 4]);
#pragma unroll
        for (int kk = 0; kk < 4; ++kk)
#pragma unroll
            for (int i = 0; i < 4; ++i)
#pragma unroll
                for (int m = 0; m < 4; ++m)
                    acc[i][m] = fmaf(qv[i][kk], sv[kk][m], acc[i][m]);
    }
#pragma unroll
    for (int i = 0; i < 4; ++i) {
        const float dinv = 1.f / denl[ty * 4 + i];
#pragma unroll
        for (int m = 0; m < 4; ++m)
            Ob[((size_t)g * 64 + ty * 4 + i) * KDIM + tx * 4 + m] = f2bf(acc[i][m] * dinv);
    }
}

// ---------------- Kernel 5: output projection (bf16 MFMA, single-shot) ----------------
// out[16384,1024] = Ob @ Woh^T. BM=64, BN=256, K=64; grid=1024, 4 waves.
__global__ __launch_bounds__(256) void k_outproj(
    const ushort* __restrict__ Ob, const ushort* __restrict__ Woh,
    float* __restrict__ out)
{
    __shared__ ushort os[8 * 512];    // 8 KB
    __shared__ ushort wos[32 * 512];  // 32 KB
    const int t = threadIdx.x, w = t >> 6, l = t & 63;
    const int row0 = (blockIdx.x >> 2) * 64;
    const int c0 = (blockIdx.x & 3) * 256;

    {
        short8v otmp[2];
#pragma unroll
        for (int i = 0; i < 2; ++i) {
            const int s = t + i * 256;
            const int f = s >> 6;
            const int row = row0 + (f >> 1) * 16 + (s & 15);
            const int kk = (f & 1) * 32 + ((s >> 4) & 3) * 8;
            otmp[i] = *(const short8v*)&Ob[(size_t)row * KDIM + kk];
        }
        short8v wtmp[8];
#pragma unroll
        for (int i = 0; i < 8; ++i) {
            const int s = t + i * 256;
            const int f = s >> 6;
            const int n = c0 + (f >> 1) * 16 + (s & 15);
            const int kk = (f & 1) * 32 + ((s >> 4) & 3) * 8;
            wtmp[i] = *(const short8v*)&Woh[(size_t)n * KDIM + kk];
        }
#pragma unroll
        for (int i = 0; i < 2; ++i) *(short8v*)&os[(t + i * 256) * 8] = otmp[i];
#pragma unroll
        for (int i = 0; i < 8; ++i) *(short8v*)&wos[(t + i * 256) * 8] = wtmp[i];
    }
    __syncthreads();

    f32x4 acc[4][4];
#pragma unroll
    for (int r = 0; r < 4; ++r)
#pragma unroll
        for (int c = 0; c < 4; ++c) acc[r][c] = (f32x4){0.f, 0.f, 0.f, 0.f};
#pragma unroll
    for (int ks = 0; ks < 2; ++ks) {
        short8v a[4], b[4];
#pragma unroll
        for (int r = 0; r < 4; ++r)
            a[r] = *(const short8v*)&os[((r * 2 + ks) * 64 + l) * 8];
#pragma unroll
        for (int c = 0; c < 4; ++c) {
            const int cf = w * 4 + c;
            b[c] = *(const short8v*)&wos[((cf * 2 + ks) * 64 + l) * 8];
        }
#pragma unroll
        for (int c = 0; c < 4; ++c)
#pragma unroll
            for (int r = 0; r < 4; ++r)
                acc[r][c] = MFMA16(a[r], b[c], acc[r][c], 0, 0, 0);
    }
#pragma unroll
    for (int r = 0; r < 4; ++r) {
#pragma unroll
        for (int c = 0; c < 4; ++c) {
            const int col = c0 + (w * 4 + c) * 16 + (l & 15);
#pragma unroll
            for (int q = 0; q < 4; ++q) {
                const int row = row0 + r * 16 + ((l >> 4) << 2) + q;
                out[(size_t)row * DDIM + col] = acc[r][c][q];
            }
        }
    }
}

extern "C" void kernel_launch(void* const* d_in, const int* in_sizes, int n_in,
                              void* d_out, int out_size, void* d_ws, size_t ws_size,
                              hipStream_t stream)
{
    const float* x  = (const float*)d_in[0];
    const float* Wq = (const float*)d_in[1];
    const float* Wk = (const float*)d_in[2];
    const float* Wv = (const float*)d_in[3];
    const float* Wo = (const float*)d_in[4];
    float* out = (float*)d_out;

    float* ws  = (float*)d_ws;
    float* Q   = ws;                                   // 1M f32
    float* Kf  = Q   + (size_t)MROWS * KDIM;           // 1M
    float* V   = Kf  + (size_t)MROWS * KDIM;           // 1M
    float* KVc = V   + (size_t)MROWS * KDIM;           // 1M
    float* Sst = KVc + (size_t)TCHUNK * KDIM * KDIM;   // 1M
    float* Ksc = Sst + (size_t)TCHUNK * KDIM * KDIM;   // 16K
    float* Kss = Ksc + (size_t)TCHUNK * KDIM;          // 16K
    ushort* Obf = (ushort*)(Kss + (size_t)TCHUNK * KDIM);  // 1M bf16
    ushort* Wh  = Obf + (size_t)MROWS * KDIM;              // 192*1024 bf16
    ushort* Woh = Wh  + (size_t)192 * DDIM;                // 1024*64 bf16

    k_wconv<<<dim3(448), dim3(256), 0, stream>>>(Wq, Wk, Wv, Wo, Wh, Woh);
    k_proj<<<dim3(256), dim3(256), 0, stream>>>(x, Wh, Q, Kf, V);
    k_chunksum<<<dim3(TCHUNK), dim3(256), 0, stream>>>(Kf, V, KVc, Ksc);
    k_scan<<<dim3(BB * 65), dim3(64), 0, stream>>>(KVc, Ksc, Sst, Kss);
    k_intra<<<dim3(TCHUNK), dim3(256), 0, stream>>>(Q, Kf, V, Sst, Kss, Obf);
    k_outproj<<<dim3((MROWS / 64) * (DDIM / 256)), dim3(256), 0, stream>>>(Obf, Woh, out);
}